// Round 1
// baseline (38.726 us; speedup 1.0000x reference)
//
#include <hip/hip_runtime.h>

// x <- relu(w[i]*x + b[i]) for i in 0..5, fused elementwise chain.
// N = 2^25 fp32 elements (128 MB). Memory-bound: 256 MB total traffic.

#define DEPTH 6

__global__ __launch_bounds__(256) void chain6_kernel(
    const float4* __restrict__ x,
    const float*  __restrict__ w,
    const float*  __restrict__ b,
    float4* __restrict__ out,
    int n4)
{
    // w/b are 6 scalars each: uniform loads, L2-broadcast, negligible cost.
    float wr[DEPTH], br[DEPTH];
#pragma unroll
    for (int i = 0; i < DEPTH; ++i) { wr[i] = w[i]; br[i] = b[i]; }

    int idx    = blockIdx.x * blockDim.x + threadIdx.x;
    int stride = gridDim.x * blockDim.x;

    for (int i = idx; i < n4; i += stride) {
        float4 v = x[i];
#pragma unroll
        for (int d = 0; d < DEPTH; ++d) {
            v.x = fmaxf(fmaf(wr[d], v.x, br[d]), 0.0f);
            v.y = fmaxf(fmaf(wr[d], v.y, br[d]), 0.0f);
            v.z = fmaxf(fmaf(wr[d], v.z, br[d]), 0.0f);
            v.w = fmaxf(fmaf(wr[d], v.w, br[d]), 0.0f);
        }
        out[i] = v;
    }
}

extern "C" void kernel_launch(void* const* d_in, const int* in_sizes, int n_in,
                              void* d_out, int out_size, void* d_ws, size_t ws_size,
                              hipStream_t stream)
{
    const float* x = (const float*)d_in[0];
    const float* w = (const float*)d_in[1];
    const float* b = (const float*)d_in[2];
    float* out = (float*)d_out;

    int n  = in_sizes[0];      // 33554432, divisible by 4
    int n4 = n / 4;

    const int block = 256;
    // Cap grid at ~8 blocks/CU * 256 CUs; grid-stride the rest.
    int grid = (n4 + block - 1) / block;
    if (grid > 2048) grid = 2048;

    chain6_kernel<<<grid, block, 0, stream>>>(
        (const float4*)x, w, b, (float4*)out, n4);
}